// Round 1
// baseline (15508.658 us; speedup 1.0000x reference)
//
#include <hip/hip_runtime.h>

#define N_USERS 100000
#define N_ITEMS 50000
#define N_NODES 150000
// DIM = 64 -> 16 float4 per row

// ---------------------------------------------------------------------------
// init: cur_ui = concat(user_emb, item_emb); acc_ui (=d_out) = same
__global__ void init_node_kernel(const float4* __restrict__ user_emb,
                                 const float4* __restrict__ item_emb,
                                 float4* __restrict__ cur,
                                 float4* __restrict__ acc) {
    int i = blockIdx.x * blockDim.x + threadIdx.x;
    const int n = N_NODES * 16;
    if (i >= n) return;
    float4 v = (i < N_USERS * 16) ? user_emb[i] : item_emb[i - N_USERS * 16];
    cur[i] = v;
    acc[i] = v;
}

// init: cur_ii = item_emb; acc_ii = item_emb
__global__ void init_item_kernel(const float4* __restrict__ item_emb,
                                 float4* __restrict__ cur,
                                 float4* __restrict__ acc) {
    int i = blockIdx.x * blockDim.x + threadIdx.x;
    const int n = N_ITEMS * 16;
    if (i >= n) return;
    float4 v = item_emb[i];
    cur[i] = v;
    acc[i] = v;
}

// ---------------------------------------------------------------------------
// COO SpMM scatter: y[dst] += val * x[src]. 16 lanes per edge, float4 gather,
// 4 fp32 hardware atomics per lane.
__global__ void spmm_scatter_kernel(const int* __restrict__ src,
                                    const int* __restrict__ dst,
                                    const float* __restrict__ val,
                                    const float* __restrict__ x,
                                    float* __restrict__ y,
                                    int nnz) {
    long long t = (long long)blockIdx.x * blockDim.x + threadIdx.x;
    int e = (int)(t >> 4);
    if (e >= nnz) return;
    int lane = (int)(t & 15);

    int s = src[e];
    int d = dst[e];
    float v = val[e];

    float4 xv = ((const float4*)x)[(long long)s * 16 + lane];
    float* yp = y + (long long)d * 64 + lane * 4;
    unsafeAtomicAdd(yp + 0, v * xv.x);
    unsafeAtomicAdd(yp + 1, v * xv.y);
    unsafeAtomicAdd(yp + 2, v * xv.z);
    unsafeAtomicAdd(yp + 3, v * xv.w);
}

// acc += nxt
__global__ void axpy_kernel(float4* __restrict__ acc,
                            const float4* __restrict__ nxt,
                            int n4) {
    int i = blockIdx.x * blockDim.x + threadIdx.x;
    if (i >= n4) return;
    float4 a = acc[i];
    float4 b = nxt[i];
    a.x += b.x; a.y += b.y; a.z += b.z; a.w += b.w;
    acc[i] = a;
}

// ---------------------------------------------------------------------------
// epilogue: users: out *= 1/4
//           items: out = 0.5*(acc_ui/4) + 0.5*(acc_ii/3) = 0.125*out + acc_ii/6
__global__ void final_kernel(float4* __restrict__ out,
                             const float4* __restrict__ acc_ii) {
    int i = blockIdx.x * blockDim.x + threadIdx.x;
    const int n = N_NODES * 16;
    if (i >= n) return;
    if (i < N_USERS * 16) {
        float4 a = out[i];
        a.x *= 0.25f; a.y *= 0.25f; a.z *= 0.25f; a.w *= 0.25f;
        out[i] = a;
    } else {
        float4 a = out[i];
        float4 b = acc_ii[i - N_USERS * 16];
        const float wa = 0.125f;          // 0.5 * (1/4)
        const float wb = 0.5f / 3.0f;     // 0.5 * (1/3)
        a.x = wa * a.x + wb * b.x;
        a.y = wa * a.y + wb * b.y;
        a.z = wa * a.z + wb * b.z;
        a.w = wa * a.w + wb * b.w;
        out[i] = a;
    }
}

// ---------------------------------------------------------------------------
extern "C" void kernel_launch(void* const* d_in, const int* in_sizes, int n_in,
                              void* d_out, int out_size, void* d_ws, size_t ws_size,
                              hipStream_t stream) {
    const float* user_emb = (const float*)d_in[0];
    const float* item_emb = (const float*)d_in[1];
    const float* ui_val   = (const float*)d_in[2];
    const float* ii_val   = (const float*)d_in[3];
    const int*   ui_src   = (const int*)d_in[4];
    const int*   ui_dst   = (const int*)d_in[5];
    const int*   ii_src   = (const int*)d_in[6];
    const int*   ii_dst   = (const int*)d_in[7];
    float* out = (float*)d_out;

    const int ui_nnz = in_sizes[2];
    const int ii_nnz = in_sizes[3];

    // workspace layout (floats): curU[9.6M] nxtU[9.6M] curI[3.2M] nxtI[3.2M] accI[3.2M]
    float* ws   = (float*)d_ws;
    float* curU = ws;
    float* nxtU = ws + (size_t)N_NODES * 64;
    float* curI = ws + (size_t)N_NODES * 64 * 2;
    float* nxtI = curI + (size_t)N_ITEMS * 64;
    float* accI = curI + (size_t)N_ITEMS * 64 * 2;

    const int n4_nodes = N_NODES * 16;
    const int n4_items = N_ITEMS * 16;
    const int B = 256;

    // init
    init_node_kernel<<<(n4_nodes + B - 1) / B, B, 0, stream>>>(
        (const float4*)user_emb, (const float4*)item_emb, (float4*)curU, (float4*)out);
    init_item_kernel<<<(n4_items + B - 1) / B, B, 0, stream>>>(
        (const float4*)item_emb, (float4*)curI, (float4*)accI);

    // UI graph: 3 layers
    {
        float* a = curU;
        float* b = nxtU;
        long long nt = (long long)ui_nnz * 16;
        int grid = (int)((nt + B - 1) / B);
        for (int l = 0; l < 3; ++l) {
            hipMemsetAsync(b, 0, (size_t)N_NODES * 64 * sizeof(float), stream);
            spmm_scatter_kernel<<<grid, B, 0, stream>>>(ui_src, ui_dst, ui_val, a, b, ui_nnz);
            axpy_kernel<<<(n4_nodes + B - 1) / B, B, 0, stream>>>((float4*)out, (const float4*)b, n4_nodes);
            float* t = a; a = b; b = t;
        }
    }

    // II graph: 2 layers
    {
        float* a = curI;
        float* b = nxtI;
        long long nt = (long long)ii_nnz * 16;
        int grid = (int)((nt + B - 1) / B);
        for (int l = 0; l < 2; ++l) {
            hipMemsetAsync(b, 0, (size_t)N_ITEMS * 64 * sizeof(float), stream);
            spmm_scatter_kernel<<<grid, B, 0, stream>>>(ii_src, ii_dst, ii_val, a, b, ii_nnz);
            axpy_kernel<<<(n4_items + B - 1) / B, B, 0, stream>>>((float4*)accI, (const float4*)b, n4_items);
            float* t = a; a = b; b = t;
        }
    }

    // epilogue
    final_kernel<<<(n4_nodes + B - 1) / B, B, 0, stream>>>((float4*)out, (const float4*)accI);
}

// Round 2
// 1825.031 us; speedup vs baseline: 8.4978x; 8.4978x over previous
//
#include <hip/hip_runtime.h>
#include <hip/hip_fp16.h>

#define N_USERS 100000
#define N_ITEMS 50000
#define N_NODES 150000
#define UI_NNZ 5000000
#define II_NNZ 1600000

// ---------------------------------------------------------------------------
// init: curU = concat(user_emb, item_emb); acc (=d_out) = same
__global__ void init_concat(const float4* __restrict__ user_emb,
                            const float4* __restrict__ item_emb,
                            float4* __restrict__ cur,
                            float4* __restrict__ acc) {
    int i = blockIdx.x * blockDim.x + threadIdx.x;
    const int n = N_NODES * 16;
    if (i >= n) return;
    float4 v = (i < N_USERS * 16) ? user_emb[i] : item_emb[i - N_USERS * 16];
    cur[i] = v;
    acc[i] = v;
}

// histogram of dst
__global__ void hist_kernel(const int* __restrict__ dst, int* __restrict__ counts, int nnz) {
    int e = blockIdx.x * blockDim.x + threadIdx.x;
    if (e < nnz) atomicAdd(&counts[dst[e]], 1);
}

// scan1: per-block (1024 elems) exclusive scan in place; block totals -> bsum
__global__ void scan1_kernel(int* __restrict__ data, int* __restrict__ bsum, int n) {
    __shared__ int s[256];
    int tid = threadIdx.x;
    int base = blockIdx.x * 1024 + tid * 4;
    int a0 = (base + 0 < n) ? data[base + 0] : 0;
    int a1 = (base + 1 < n) ? data[base + 1] : 0;
    int a2 = (base + 2 < n) ? data[base + 2] : 0;
    int a3 = (base + 3 < n) ? data[base + 3] : 0;
    int tsum = a0 + a1 + a2 + a3;
    s[tid] = tsum;
    __syncthreads();
    for (int off = 1; off < 256; off <<= 1) {
        int v = (tid >= off) ? s[tid - off] : 0;
        __syncthreads();
        s[tid] += v;
        __syncthreads();
    }
    int excl = s[tid] - tsum;   // exclusive prefix within block
    if (base + 0 < n) data[base + 0] = excl;
    if (base + 1 < n) data[base + 1] = excl + a0;
    if (base + 2 < n) data[base + 2] = excl + a0 + a1;
    if (base + 3 < n) data[base + 3] = excl + a0 + a1 + a2;
    if (tid == 255) bsum[blockIdx.x] = s[255];   // block total
}

// scan2: exclusive scan of block sums (nB <= 256), single block
__global__ void scan2_kernel(int* __restrict__ bsum, int nB) {
    __shared__ int s[256];
    int tid = threadIdx.x;
    int v = (tid < nB) ? bsum[tid] : 0;
    s[tid] = v;
    __syncthreads();
    for (int off = 1; off < 256; off <<= 1) {
        int u = (tid >= off) ? s[tid - off] : 0;
        __syncthreads();
        s[tid] += u;
        __syncthreads();
    }
    if (tid < nB) bsum[tid] = s[tid] - v;
}

// scan3: add scanned block offsets
__global__ void scan3_kernel(int* __restrict__ data, const int* __restrict__ bsum, int n) {
    int i = blockIdx.x * blockDim.x + threadIdx.x;
    if (i < n) data[i] += bsum[i >> 10];
}

// scatter edges into dst-sorted order. Mutates rowptr: afterwards rowptr[i] = end of row i.
__global__ void scatter_kernel(const int* __restrict__ src, const int* __restrict__ dst,
                               const float* __restrict__ val,
                               int* __restrict__ rowptr,
                               unsigned* __restrict__ esrc, __half* __restrict__ eval,
                               int nnz) {
    int e = blockIdx.x * blockDim.x + threadIdx.x;
    if (e >= nnz) return;
    int d = dst[e];
    int pos = atomicAdd(&rowptr[d], 1);
    esrc[pos] = (unsigned)src[e];
    eval[pos] = __float2half(val[e]);
}

// ---------------------------------------------------------------------------
// pull SpMM: one 64-lane wave per row, lane = column. Fused acc += scale*sum.
// rowend[i] = end offset of row i (start = rowend[i-1], row 0 starts at 0).
__global__ void spmm_pull(const int* __restrict__ rowend,
                          const unsigned* __restrict__ esrc,
                          const __half* __restrict__ eval,
                          const float* __restrict__ x,
                          float* __restrict__ y,
                          float* __restrict__ acc, float acc_scale,
                          int n_rows) {
    int row = blockIdx.x * 4 + (threadIdx.x >> 6);
    if (row >= n_rows) return;
    int col = threadIdx.x & 63;
    int start = (row == 0) ? 0 : rowend[row - 1];
    int end = rowend[row];
    float s0 = 0.f, s1 = 0.f;
    int j = start;
    for (; j + 2 <= end; j += 2) {
        unsigned a = esrc[j];
        unsigned b = esrc[j + 1];
        float va = __half2float(eval[j]);
        float vb = __half2float(eval[j + 1]);
        s0 = fmaf(va, x[(size_t)a * 64 + col], s0);
        s1 = fmaf(vb, x[(size_t)b * 64 + col], s1);
    }
    if (j < end) {
        s0 = fmaf(__half2float(eval[j]), x[(size_t)esrc[j] * 64 + col], s0);
    }
    float sum = s0 + s1;
    size_t o = (size_t)row * 64 + col;
    y[o] = sum;
    acc[o] += acc_scale * sum;
}

// ---------------------------------------------------------------------------
// after UI phase: users *= 1/4 ; items = 0.125*acc_ui + item_emb/6
__global__ void scale_kernel(float* __restrict__ out, const float* __restrict__ item_emb) {
    int i = blockIdx.x * blockDim.x + threadIdx.x;
    const int n = N_NODES * 64;
    if (i >= n) return;
    if (i < N_USERS * 64) {
        out[i] *= 0.25f;
    } else {
        out[i] = 0.125f * out[i] + (1.0f / 6.0f) * item_emb[i - N_USERS * 64];
    }
}

// ---------------------------------------------------------------------------
extern "C" void kernel_launch(void* const* d_in, const int* in_sizes, int n_in,
                              void* d_out, int out_size, void* d_ws, size_t ws_size,
                              hipStream_t stream) {
    const float* user_emb = (const float*)d_in[0];
    const float* item_emb = (const float*)d_in[1];
    const float* ui_val   = (const float*)d_in[2];
    const float* ii_val   = (const float*)d_in[3];
    const int*   ui_src   = (const int*)d_in[4];
    const int*   ui_dst   = (const int*)d_in[5];
    const int*   ii_src   = (const int*)d_in[6];
    const int*   ii_dst   = (const int*)d_in[7];
    float* out = (float*)d_out;

    const int ui_nnz = in_sizes[2];
    const int ii_nnz = in_sizes[3];

    // ---- workspace layout (peak 107.4 MB; round-1 proved ws >= 115.2 MB) ----
    char* base = (char*)d_ws;
    const size_t SZ_NODE = (size_t)N_NODES * 64 * sizeof(float);   // 38.4 MB
    const size_t SZ_ITEM = (size_t)N_ITEMS * 64 * sizeof(float);   // 12.8 MB
    // phase A (UI)
    float*    curU   = (float*)base;
    float*    nxtU   = (float*)(base + SZ_NODE);
    unsigned* uiSrc  = (unsigned*)(base + 2 * SZ_NODE);
    __half*   uiVal  = (__half*)(base + 2 * SZ_NODE + 4ull * UI_NNZ);
    int*      uiRow  = (int*)(base + 2 * SZ_NODE + 6ull * UI_NNZ);
    int*      uiBsum = (int*)(base + 2 * SZ_NODE + 6ull * UI_NNZ + (size_t)N_NODES * 4);
    // phase B (II) — overlays curU/nxtU region (dead after UI layer 3)
    float*    bufA   = (float*)base;
    float*    bufB   = (float*)(base + SZ_ITEM);
    unsigned* iiSrc  = (unsigned*)(base + 2 * SZ_ITEM);
    __half*   iiVal  = (__half*)(base + 2 * SZ_ITEM + 4ull * II_NNZ);
    int*      iiRow  = (int*)(base + 2 * SZ_ITEM + 6ull * II_NNZ);
    int*      iiBsum = (int*)(base + 2 * SZ_ITEM + 6ull * II_NNZ + (size_t)N_ITEMS * 4);

    const int B = 256;
    const int nB_ui = (N_NODES + 1023) / 1024;   // 147
    const int nB_ii = (N_ITEMS + 1023) / 1024;   // 49

    // ======================= Phase A: UI graph (3 layers) ====================
    init_concat<<<(N_NODES * 16 + B - 1) / B, B, 0, stream>>>(
        (const float4*)user_emb, (const float4*)item_emb, (float4*)curU, (float4*)out);

    hipMemsetAsync(uiRow, 0, (size_t)N_NODES * sizeof(int), stream);
    hist_kernel<<<(ui_nnz + B - 1) / B, B, 0, stream>>>(ui_dst, uiRow, ui_nnz);
    scan1_kernel<<<nB_ui, B, 0, stream>>>(uiRow, uiBsum, N_NODES);
    scan2_kernel<<<1, B, 0, stream>>>(uiBsum, nB_ui);
    scan3_kernel<<<(N_NODES + B - 1) / B, B, 0, stream>>>(uiRow, uiBsum, N_NODES);
    scatter_kernel<<<(ui_nnz + B - 1) / B, B, 0, stream>>>(
        ui_src, ui_dst, ui_val, uiRow, uiSrc, uiVal, ui_nnz);

    const int gridPullU = (N_NODES + 3) / 4;
    spmm_pull<<<gridPullU, B, 0, stream>>>(uiRow, uiSrc, uiVal, curU, nxtU, out, 1.0f, N_NODES);
    spmm_pull<<<gridPullU, B, 0, stream>>>(uiRow, uiSrc, uiVal, nxtU, curU, out, 1.0f, N_NODES);
    spmm_pull<<<gridPullU, B, 0, stream>>>(uiRow, uiSrc, uiVal, curU, nxtU, out, 1.0f, N_NODES);

    // users *= 1/4 ; items = 0.125*acc_ui + item_emb/6
    scale_kernel<<<(N_NODES * 64 + B - 1) / B, B, 0, stream>>>(out, item_emb);

    // ======================= Phase B: II graph (2 layers) ====================
    hipMemsetAsync(iiRow, 0, (size_t)N_ITEMS * sizeof(int), stream);
    hist_kernel<<<(ii_nnz + B - 1) / B, B, 0, stream>>>(ii_dst, iiRow, ii_nnz);
    scan1_kernel<<<nB_ii, B, 0, stream>>>(iiRow, iiBsum, N_ITEMS);
    scan2_kernel<<<1, B, 0, stream>>>(iiBsum, nB_ii);
    scan3_kernel<<<(N_ITEMS + B - 1) / B, B, 0, stream>>>(iiRow, iiBsum, N_ITEMS);
    scatter_kernel<<<(ii_nnz + B - 1) / B, B, 0, stream>>>(
        ii_src, ii_dst, ii_val, iiRow, iiSrc, iiVal, ii_nnz);

    const int gridPullI = (N_ITEMS + 3) / 4;
    float* outItems = out + (size_t)N_USERS * 64;
    // layer 1 reads item_emb directly (no curI copy needed)
    spmm_pull<<<gridPullI, B, 0, stream>>>(iiRow, iiSrc, iiVal, item_emb, bufA, outItems, 1.0f / 6.0f, N_ITEMS);
    spmm_pull<<<gridPullI, B, 0, stream>>>(iiRow, iiSrc, iiVal, bufA, bufB, outItems, 1.0f / 6.0f, N_ITEMS);
}

// Round 3
// 1576.804 us; speedup vs baseline: 9.8355x; 1.1574x over previous
//
#include <hip/hip_runtime.h>
#include <hip/hip_fp16.h>

#define N_USERS 100000
#define N_ITEMS 50000
#define N_NODES 150000
#define UI_NNZ 5000000
#define II_NNZ 1600000

// pack 4 floats -> 4 halves in a uint2
__device__ inline uint2 pack4h(float4 v) {
    uint2 h;
    h.x = (unsigned)__half_as_ushort(__float2half(v.x)) |
          ((unsigned)__half_as_ushort(__float2half(v.y)) << 16);
    h.y = (unsigned)__half_as_ushort(__float2half(v.z)) |
          ((unsigned)__half_as_ushort(__float2half(v.w)) << 16);
    return h;
}

// ---------------------------------------------------------------------------
// init: curU(fp16) = concat(user,item); acc(=d_out, fp32) = same; itemH(fp16) = item_emb
__global__ void init_concat(const float4* __restrict__ user_emb,
                            const float4* __restrict__ item_emb,
                            uint2* __restrict__ curH,
                            float4* __restrict__ acc,
                            uint2* __restrict__ itemH) {
    int i = blockIdx.x * blockDim.x + threadIdx.x;   // float4 index
    const int n = N_NODES * 16;
    if (i >= n) return;
    bool is_item = (i >= N_USERS * 16);
    float4 v = is_item ? item_emb[i - N_USERS * 16] : user_emb[i];
    acc[i] = v;
    uint2 h = pack4h(v);
    curH[i] = h;
    if (is_item) itemH[i - N_USERS * 16] = h;
}

// histogram of dst
__global__ void hist_kernel(const int* __restrict__ dst, int* __restrict__ counts, int nnz) {
    int e = blockIdx.x * blockDim.x + threadIdx.x;
    if (e < nnz) atomicAdd(&counts[dst[e]], 1);
}

// scan1: per-block (1024 elems) exclusive scan in place; block totals -> bsum
__global__ void scan1_kernel(int* __restrict__ data, int* __restrict__ bsum, int n) {
    __shared__ int s[256];
    int tid = threadIdx.x;
    int base = blockIdx.x * 1024 + tid * 4;
    int a0 = (base + 0 < n) ? data[base + 0] : 0;
    int a1 = (base + 1 < n) ? data[base + 1] : 0;
    int a2 = (base + 2 < n) ? data[base + 2] : 0;
    int a3 = (base + 3 < n) ? data[base + 3] : 0;
    int tsum = a0 + a1 + a2 + a3;
    s[tid] = tsum;
    __syncthreads();
    for (int off = 1; off < 256; off <<= 1) {
        int v = (tid >= off) ? s[tid - off] : 0;
        __syncthreads();
        s[tid] += v;
        __syncthreads();
    }
    int excl = s[tid] - tsum;
    if (base + 0 < n) data[base + 0] = excl;
    if (base + 1 < n) data[base + 1] = excl + a0;
    if (base + 2 < n) data[base + 2] = excl + a0 + a1;
    if (base + 3 < n) data[base + 3] = excl + a0 + a1 + a2;
    if (tid == 255) bsum[blockIdx.x] = s[255];
}

// scan2: exclusive scan of block sums (nB <= 256), single block
__global__ void scan2_kernel(int* __restrict__ bsum, int nB) {
    __shared__ int s[256];
    int tid = threadIdx.x;
    int v = (tid < nB) ? bsum[tid] : 0;
    s[tid] = v;
    __syncthreads();
    for (int off = 1; off < 256; off <<= 1) {
        int u = (tid >= off) ? s[tid - off] : 0;
        __syncthreads();
        s[tid] += u;
        __syncthreads();
    }
    if (tid < nB) bsum[tid] = s[tid] - v;
}

// scan3: add scanned block offsets
__global__ void scan3_kernel(int* __restrict__ data, const int* __restrict__ bsum, int n) {
    int i = blockIdx.x * blockDim.x + threadIdx.x;
    if (i < n) data[i] += bsum[i >> 10];
}

// scatter edges into dst-sorted order, ONE 8B record per edge.
// Mutates rowptr: afterwards rowptr[i] = end of row i.
__global__ void scatter_kernel(const int* __restrict__ src, const int* __restrict__ dst,
                               const float* __restrict__ val,
                               int* __restrict__ rowptr,
                               uint2* __restrict__ edges,
                               int nnz) {
    int e = blockIdx.x * blockDim.x + threadIdx.x;
    if (e >= nnz) return;
    int d = dst[e];
    int pos = atomicAdd(&rowptr[d], 1);
    uint2 r;
    r.x = (unsigned)src[e];
    r.y = (unsigned)__half_as_ushort(__float2half(val[e]));
    edges[pos] = r;
}

// ---------------------------------------------------------------------------
// pull SpMM (fp16 x): one 64-lane wave per row, lane = column.
// y (fp16, optional) = row result; acc(fp32) += scale * result.
__global__ void spmm_pull(const int* __restrict__ rowend,
                          const uint2* __restrict__ edges,
                          const __half* __restrict__ x,
                          __half* __restrict__ y,
                          float* __restrict__ acc, float acc_scale,
                          int n_rows) {
    int row = blockIdx.x * 4 + (threadIdx.x >> 6);
    if (row >= n_rows) return;
    int col = threadIdx.x & 63;
    int start = (row == 0) ? 0 : rowend[row - 1];
    int end = rowend[row];
    float s0 = 0.f, s1 = 0.f, s2 = 0.f, s3 = 0.f;
    int j = start;
    for (; j + 4 <= end; j += 4) {
        uint2 e0 = edges[j + 0];
        uint2 e1 = edges[j + 1];
        uint2 e2 = edges[j + 2];
        uint2 e3 = edges[j + 3];
        float x0 = __half2float(x[(size_t)e0.x * 64 + col]);
        float x1 = __half2float(x[(size_t)e1.x * 64 + col]);
        float x2 = __half2float(x[(size_t)e2.x * 64 + col]);
        float x3 = __half2float(x[(size_t)e3.x * 64 + col]);
        s0 = fmaf(__half2float(__ushort_as_half((unsigned short)e0.y)), x0, s0);
        s1 = fmaf(__half2float(__ushort_as_half((unsigned short)e1.y)), x1, s1);
        s2 = fmaf(__half2float(__ushort_as_half((unsigned short)e2.y)), x2, s2);
        s3 = fmaf(__half2float(__ushort_as_half((unsigned short)e3.y)), x3, s3);
    }
    for (; j < end; ++j) {
        uint2 e0 = edges[j];
        s0 = fmaf(__half2float(__ushort_as_half((unsigned short)e0.y)),
                  __half2float(x[(size_t)e0.x * 64 + col]), s0);
    }
    float sum = (s0 + s1) + (s2 + s3);
    size_t o = (size_t)row * 64 + col;
    if (y) y[o] = __float2half(sum);
    acc[o] += acc_scale * sum;
}

// ---------------------------------------------------------------------------
// after UI phase: users *= 1/4 ; items = 0.125*acc_ui + item_emb/6
__global__ void scale_kernel(float* __restrict__ out, const float* __restrict__ item_emb) {
    int i = blockIdx.x * blockDim.x + threadIdx.x;
    const int n = N_NODES * 64;
    if (i >= n) return;
    if (i < N_USERS * 64) {
        out[i] *= 0.25f;
    } else {
        out[i] = 0.125f * out[i] + (1.0f / 6.0f) * item_emb[i - N_USERS * 64];
    }
}

// ---------------------------------------------------------------------------
extern "C" void kernel_launch(void* const* d_in, const int* in_sizes, int n_in,
                              void* d_out, int out_size, void* d_ws, size_t ws_size,
                              hipStream_t stream) {
    const float* user_emb = (const float*)d_in[0];
    const float* item_emb = (const float*)d_in[1];
    const float* ui_val   = (const float*)d_in[2];
    const float* ii_val   = (const float*)d_in[3];
    const int*   ui_src   = (const int*)d_in[4];
    const int*   ui_dst   = (const int*)d_in[5];
    const int*   ii_src   = (const int*)d_in[6];
    const int*   ii_dst   = (const int*)d_in[7];
    float* out = (float*)d_out;

    const int ui_nnz = in_sizes[2];
    const int ii_nnz = in_sizes[3];

    // ---- workspace layout (~111 MB; >=115.2 MB proven available) ----
    char* base = (char*)d_ws;
    size_t off = 0;
    __half* curU   = (__half*)(base + off); off += (size_t)N_NODES * 64 * 2;   // 19.2 MB
    __half* nxtU   = (__half*)(base + off); off += (size_t)N_NODES * 64 * 2;   // 19.2 MB
    uint2*  uiEdge = (uint2*)(base + off);  off += 8ull * UI_NNZ;              // 40.0 MB
    int*    uiRow  = (int*)(base + off);    off += (size_t)N_NODES * 4;        // 0.6 MB
    int*    uiBsum = (int*)(base + off);    off += 1024;
    __half* itemH  = (__half*)(base + off); off += (size_t)N_ITEMS * 64 * 2;   // 6.4 MB
    uint2*  iiEdge = (uint2*)(base + off);  off += 8ull * II_NNZ;              // 12.8 MB
    int*    iiRow  = (int*)(base + off);    off += (size_t)N_ITEMS * 4;        // 0.2 MB
    int*    iiBsum = (int*)(base + off);    off += 1024;
    __half* bufA   = (__half*)(base + off); off += (size_t)N_ITEMS * 64 * 2;   // 6.4 MB
    __half* bufB   = (__half*)(base + off); off += (size_t)N_ITEMS * 64 * 2;   // 6.4 MB

    const int B = 256;
    const int nB_ui = (N_NODES + 1023) / 1024;   // 147
    const int nB_ii = (N_ITEMS + 1023) / 1024;   // 49

    // ======================= Phase A: UI graph (3 layers) ====================
    init_concat<<<(N_NODES * 16 + B - 1) / B, B, 0, stream>>>(
        (const float4*)user_emb, (const float4*)item_emb,
        (uint2*)curU, (float4*)out, (uint2*)itemH);

    hipMemsetAsync(uiRow, 0, (size_t)N_NODES * sizeof(int), stream);
    hist_kernel<<<(ui_nnz + B - 1) / B, B, 0, stream>>>(ui_dst, uiRow, ui_nnz);
    scan1_kernel<<<nB_ui, B, 0, stream>>>(uiRow, uiBsum, N_NODES);
    scan2_kernel<<<1, B, 0, stream>>>(uiBsum, nB_ui);
    scan3_kernel<<<(N_NODES + B - 1) / B, B, 0, stream>>>(uiRow, uiBsum, N_NODES);
    scatter_kernel<<<(ui_nnz + B - 1) / B, B, 0, stream>>>(
        ui_src, ui_dst, ui_val, uiRow, uiEdge, ui_nnz);

    const int gridPullU = (N_NODES + 3) / 4;
    spmm_pull<<<gridPullU, B, 0, stream>>>(uiRow, uiEdge, curU, nxtU, out, 1.0f, N_NODES);
    spmm_pull<<<gridPullU, B, 0, stream>>>(uiRow, uiEdge, nxtU, curU, out, 1.0f, N_NODES);
    spmm_pull<<<gridPullU, B, 0, stream>>>(uiRow, uiEdge, curU, (__half*)nullptr, out, 1.0f, N_NODES);

    // users *= 1/4 ; items = 0.125*acc_ui + item_emb/6
    scale_kernel<<<(N_NODES * 64 + B - 1) / B, B, 0, stream>>>(out, item_emb);

    // ======================= Phase B: II graph (2 layers) ====================
    hipMemsetAsync(iiRow, 0, (size_t)N_ITEMS * sizeof(int), stream);
    hist_kernel<<<(ii_nnz + B - 1) / B, B, 0, stream>>>(ii_dst, iiRow, ii_nnz);
    scan1_kernel<<<nB_ii, B, 0, stream>>>(iiRow, iiBsum, N_ITEMS);
    scan2_kernel<<<1, B, 0, stream>>>(iiBsum, nB_ii);
    scan3_kernel<<<(N_ITEMS + B - 1) / B, B, 0, stream>>>(iiRow, iiBsum, N_ITEMS);
    scatter_kernel<<<(ii_nnz + B - 1) / B, B, 0, stream>>>(
        ii_src, ii_dst, ii_val, iiRow, iiEdge, ii_nnz);

    const int gridPullI = (N_ITEMS + 3) / 4;
    float* outItems = out + (size_t)N_USERS * 64;
    spmm_pull<<<gridPullI, B, 0, stream>>>(iiRow, iiEdge, itemH, bufA, outItems, 1.0f / 6.0f, N_ITEMS);
    spmm_pull<<<gridPullI, B, 0, stream>>>(iiRow, iiEdge, bufA, (__half*)nullptr, outItems, 1.0f / 6.0f, N_ITEMS);
}